// Round 12
// baseline (957.842 us; speedup 1.0000x reference)
//
#include <hip/hip_runtime.h>
#include <math.h>

constexpr int NN   = 20000;   // nodes
constexpr int EE   = 640000;  // edges
constexpr int RR   = 90;      // relations
constexpr int INF_ = 128;     // in features
constexpr int HID  = 64;      // hidden
constexpr float EPS = 1e-16f;
constexpr int E2   = 646144;  // padded edge capacity: 2524*256, >= EE + 90*63

typedef unsigned short u16;
typedef _Float16 f16;
typedef __attribute__((ext_vector_type(8))) _Float16 f16x8;
typedef __attribute__((ext_vector_type(4))) _Float16 f16x4;
typedef __attribute__((ext_vector_type(4))) float f32x4;
typedef __attribute__((ext_vector_type(4))) int ivec4;

// order-preserving float<->uint encode (monotone: f<g  <=>  f2ord(f)<f2ord(g))
__device__ inline unsigned f2ord(float f) {
    unsigned u = __float_as_uint(f);
    return (u & 0x80000000u) ? ~u : (u | 0x80000000u);
}
__device__ inline float ord2f(unsigned x) {
    unsigned u = (x & 0x80000000u) ? (x & 0x7FFFFFFFu) : ~x;
    return __uint_as_float(u);
}
// f2ord(-INF) = 0x007FFFFF — table init value
#define ORD_NEGINF 0x007FFFFFu

__global__ void k_fillrec(int4* p, int n) {
    int i = blockIdx.x * blockDim.x + threadIdx.x;
    if (i < n) { int4 r; r.x = 0; r.y = 0; r.z = 0; r.w = -1; p[i] = r; }
}

// ---------------- sort 1: by relation, segment-padded to 64 ----------------
__global__ void k_hist(const int* et, int* hist) {
    __shared__ int lh[RR];
    if (threadIdx.x < RR) lh[threadIdx.x] = 0;
    __syncthreads();
    int i = blockIdx.x * blockDim.x + threadIdx.x;
    if (i < EE) atomicAdd(&lh[et[i]], 1);
    __syncthreads();
    if (threadIdx.x < RR) atomicAdd(&hist[threadIdx.x], lh[threadIdx.x]);
}

__global__ void k_scanPad(const int* hist, int* cursor) {
    if (threadIdx.x == 0) {
        int acc = 0;
        for (int r = 0; r < RR; ++r) {
            cursor[r] = acc;
            acc += (hist[r] + 63) & ~63;   // pad each segment to 64
        }
    }
}

// sortedR records {src, dst, rel, orig}; dummies stay {0,0,0,-1}
// posS[orig] = relation-sorted position (for sorted ae scatter)
__global__ void k_scatter(const int* src, const int* dst, const int* et,
                          int* cursor, int4* sortedR, int* posS) {
    __shared__ int lh[RR];
    __shared__ int lbase[RR];
    if (threadIdx.x < RR) lh[threadIdx.x] = 0;
    __syncthreads();
    int i = blockIdx.x * blockDim.x + threadIdx.x;
    int r = et[i];
    int rank = atomicAdd(&lh[r], 1);
    __syncthreads();
    if (threadIdx.x < RR) {
        int c = lh[threadIdx.x];
        lbase[threadIdx.x] = c ? atomicAdd(&cursor[threadIdx.x], c) : 0;
    }
    __syncthreads();
    int pos = lbase[r] + rank;
    int4 rec; rec.x = src[i]; rec.y = dst[i]; rec.z = r; rec.w = i;
    sortedR[pos] = rec;
    posS[i] = pos;
}

// ---------------- sort 2: by destination ----------------
__global__ void k_histD(const int* dst, int* histD) {
    int i = blockIdx.x * blockDim.x + threadIdx.x;
    if (i < EE) atomicAdd(&histD[dst[i]], 1);
}

__global__ void k_scanD(const int* histD, int* rowptrD, int* cursorD) {
    __shared__ int part[256];
    const int CH = (NN + 255) / 256;
    int tid = threadIdx.x;
    int base = tid * CH;
    int s = 0;
    for (int j = 0; j < CH; ++j) {
        int idx = base + j;
        if (idx < NN) s += histD[idx];
    }
    part[tid] = s;
    __syncthreads();
    if (tid == 0) {
        int acc = 0;
        for (int t = 0; t < 256; ++t) { int v = part[t]; part[t] = acc; acc += v; }
    }
    __syncthreads();
    int acc = part[tid];
    for (int j = 0; j < CH; ++j) {
        int idx = base + j;
        if (idx < NN) {
            rowptrD[idx] = acc;
            cursorD[idx] = acc;
            acc += histD[idx];
        }
    }
    if (tid == 0) rowptrD[NN] = EE;
}

// rewrites sortedR[i].w = dst-sorted position (dummies keep -1);
// relD[dstpos] = relation (u16)
__global__ void k_scatterD(int4* sortedR, int* cursorD, u16* relD) {
    int i = blockIdx.x * blockDim.x + threadIdx.x;
    if (i >= E2) return;
    int4 rec = sortedR[i];
    if (rec.w < 0) return;
    int pos = atomicAdd(&cursorD[rec.y], 1);
    ((int*)(sortedR + i))[3] = pos;
    relD[pos] = (u16)rec.z;
}

// ---------------- weight folding ----------------
__global__ void k_w1(const float* att1, const float* basis1, float* w1) {
    int idx = blockIdx.x * blockDim.x + threadIdx.x;
    if (idx >= RR * 2560) return;
    int r = idx / 2560, co = idx - r * 2560;
    float acc = 0.f;
    for (int b = 0; b < 35; ++b) acc += att1[r * 35 + b] * basis1[b * 2560 + co];
    w1[idx] = acc;
}

__global__ void k_wqk1(const float* w1, const float* q1, const float* k1,
                       float* wq1, float* wk1) {
    int idx = blockIdx.x * blockDim.x + threadIdx.x;
    if (idx >= RR * 64 * 4) return;
    int t = idx & 3, c = (idx >> 2) & 63, r = idx >> 8;
    const float* wrow = w1 + (size_t)r * 2560 + c * 40;
    float aq = 0.f, ak = 0.f;
    for (int o = 0; o < 40; ++o) {
        float w = wrow[o];
        aq += w * q1[o * 4 + t];
        ak += w * k1[o * 4 + t];
    }
    wq1[idx] = aq; wk1[idx] = ak;
}

__global__ void k_wqk2(const float* w2, const float* q2, const float* k2,
                       float* wq2, float* wk2) {
    int idx = blockIdx.x * blockDim.x + threadIdx.x;
    if (idx >= RR * 80 * 2) return;
    int t = idx & 1, bc = (idx >> 1) % 80, r = idx / 160;
    int b = bc / 40, c = bc % 40;
    const float* wbase = w2 + (size_t)((r * 2 + b) * 40 + c) * 32;
    float aq = 0.f, ak = 0.f;
    for (int d = 0; d < 32; ++d) {
        float w = wbase[d];
        aq += w * q2[(b * 32 + d) * 2 + t];
        ak += w * k2[(b * 32 + d) * 2 + t];
    }
    wq2[idx] = aq; wk2[idx] = ak;
}

__global__ void k_we(const float* lew, const float* e2, float* we) {
    int idx = threadIdx.x;
    if (idx >= 32) return;
    int i = idx >> 1, t = idx & 1;
    float acc = 0.f;
    for (int j = 0; j < 64; ++j) acc += lew[i * 64 + j] * e2[j * 2 + t];
    we[idx] = acc;
}

// aeS[posS[e]][2] = edge_attr[e] @ we  — coalesced read, scattered 8B write
__global__ __launch_bounds__(256) void k_ae(const float* ea, const float* weg,
                                            const int* posS, float* aeS) {
    __shared__ float wes[32];
    if (threadIdx.x < 32) wes[threadIdx.x] = weg[threadIdx.x];
    __syncthreads();
    int e = blockIdx.x * 256 + threadIdx.x;
    if (e >= EE) return;
    const float4* ep = (const float4*)(ea + (size_t)e * 16);
    float a0 = 0.f, a1 = 0.f;
#pragma unroll
    for (int cc = 0; cc < 4; ++cc) {
        float4 v = ep[cc];
        const float* vv = (const float*)&v;
#pragma unroll
        for (int j = 0; j < 4; ++j) {
            int ii = cc * 4 + j;
            a0 = fmaf(vv[j], wes[ii * 2 + 0], a0);
            a1 = fmaf(vv[j], wes[ii * 2 + 1], a1);
        }
    }
    float2 av; av.x = a0; av.y = a1;
    *(float2*)(aeS + (size_t)posS[e] * 2) = av;
}

// f16 transposed+padded weights: w1hT[r][o(48)][k(64)]
__global__ void k_w1hT(const float* w1, f16* w1hT) {
    int idx = blockIdx.x * blockDim.x + threadIdx.x;
    if (idx >= RR * 48 * 64) return;
    int k = idx & 63, o = (idx >> 6) % 48, r = idx / (48 * 64);
    float v = (o < 40) ? w1[(size_t)r * 2560 + k * 40 + o] : 0.f;
    w1hT[idx] = (f16)v;
}

// w2hT[r][b][d(32)][c(64)]  (c = K, padded 40->64 with ZEROS — enables
// unpadded h1h B-fragment reads: garbage at K>=40 multiplies zero)
__global__ void k_w2hT(const float* w2, f16* w2hT) {
    int idx = blockIdx.x * blockDim.x + threadIdx.x;
    if (idx >= RR * 2 * 32 * 64) return;
    int c = idx & 63, d = (idx >> 6) & 31, b = (idx >> 11) & 1, r = idx >> 12;
    float v = (c < 40) ? w2[((((size_t)r * 2 + b) * 40) + c) * 32 + d] : 0.f;
    w2hT[idx] = (f16)v;
}

// hh = f16(x @ lin1_w) — single buffer for logits AND MFMA B-operand
__global__ void k_h(const float* x, const float* lin1_w, f16* hh) {
    __shared__ float xs[INF_];
    int n = blockIdx.x, t = threadIdx.x;
    xs[t]      = x[(size_t)n * INF_ + t];
    xs[t + 64] = x[(size_t)n * INF_ + t + 64];
    __syncthreads();
    float acc = 0.f;
    for (int i = 0; i < INF_; ++i) acc += xs[i] * lin1_w[i * HID + t];
    hh[(size_t)n * HID + t] = (f16)acc;
}

// ---------------- conv1 fused: s-side logit (kj) + MFMA transform ----------
// Each wave owns 64 consecutive edges (rel-uniform by 64-padding), depth-3
// pipeline. Only the SOURCE row is gathered (feeds both kj and MFMA-B); the
// dst-side logit qi is finished in k_aggr1 where the dst row is wave-local.
__global__ __launch_bounds__(256) void k_c1(const int4* sortedR, const f16* hh,
                                            const f16* w1hT, const float* wk1g,
                                            float* alpha1s, f16* outj1h) {
    __shared__ float ks[4][256];
    int wid = threadIdx.x >> 6, l = threadIdx.x & 63;
    int wbase = blockIdx.x * 256 + wid * 64;
    int r = sortedR[wbase].z;
    float* kw = ks[wid];
    for (int t = l; t < 256; t += 64)
        kw[t] = wk1g[(size_t)r * 256 + t];
    __syncthreads();
    int row16 = l & 15, g = l >> 4;
    f16x8 a[3][2];
#pragma unroll
    for (int mt = 0; mt < 3; ++mt)
#pragma unroll
        for (int kk = 0; kk < 2; ++kk)
            a[mt][kk] = *(const f16x8*)(w1hT + ((size_t)r * 48 + mt * 16 + row16) * 64 + kk * 32 + g * 8);
    ivec4 er[3];
    f16x8 vb0[3], vb1[3];

#define C1_LOAD(SLOT, T) { \
    int e0_ = wbase + (T) * 16; \
    er[SLOT] = __builtin_nontemporal_load((const ivec4*)(sortedR + e0_ + row16)); \
    int s_ = er[SLOT][0]; \
    vb0[SLOT] = *(const f16x8*)(hh + (size_t)s_ * 64 + g * 8); \
    vb1[SLOT] = *(const f16x8*)(hh + (size_t)s_ * 64 + 32 + g * 8); }

#define C1_COMP(SLOT) { \
    int pd_ = er[SLOT][3]; \
    float kj[4] = {0.f,0.f,0.f,0.f}; \
    _Pragma("unroll") for (int j = 0; j < 8; ++j) { \
        int p0 = g * 8 + j, p1 = 32 + g * 8 + j; \
        float bv0 = (float)vb0[SLOT][j], bv1 = (float)vb1[SLOT][j]; \
        _Pragma("unroll") for (int t2 = 0; t2 < 4; ++t2) \
            kj[t2] = fmaf(bv0, kw[p0 * 4 + t2], fmaf(bv1, kw[p1 * 4 + t2], kj[t2])); } \
    _Pragma("unroll") for (int t2 = 0; t2 < 4; ++t2) { \
        kj[t2] += __shfl_xor(kj[t2], 16); kj[t2] += __shfl_xor(kj[t2], 32); } \
    f32x4 acc[3]; \
    _Pragma("unroll") for (int mt = 0; mt < 3; ++mt) acc[mt] = (f32x4){0.f,0.f,0.f,0.f}; \
    _Pragma("unroll") for (int mt = 0; mt < 3; ++mt) { \
        acc[mt] = __builtin_amdgcn_mfma_f32_16x16x32_f16(a[mt][0], vb0[SLOT], acc[mt], 0, 0, 0); \
        acc[mt] = __builtin_amdgcn_mfma_f32_16x16x32_f16(a[mt][1], vb1[SLOT], acc[mt], 0, 0, 0); } \
    if (pd_ >= 0) { \
        if (l < 16) { \
            float4 av; av.x = kj[0]; av.y = kj[1]; av.z = kj[2]; av.w = kj[3]; \
            *(float4*)(alpha1s + (size_t)pd_ * 4) = av; } \
        f16* orow = outj1h + (size_t)pd_ * 40; \
        _Pragma("unroll") for (int mt = 0; mt < 3; ++mt) { \
            int col = mt * 16 + g * 4; \
            if (col < 40) { \
                f16x4 v; \
                v[0] = (f16)acc[mt][0]; v[1] = (f16)acc[mt][1]; \
                v[2] = (f16)acc[mt][2]; v[3] = (f16)acc[mt][3]; \
                *(f16x4*)(orow + col) = v; } } } }

    C1_LOAD(0, 0)
    C1_LOAD(1, 1)
    C1_LOAD(2, 2)
    C1_COMP(0)
    C1_LOAD(0, 3)
    C1_COMP(1)
    C1_COMP(2)
    C1_COMP(0)
#undef C1_LOAD
#undef C1_COMP
}

// ---------------- conv1 aggregate + dst-side logit + segment softmax --------
// Wave owns one dst. alpha1s holds kj (s-side); phase B finishes the logit:
// qi = h[dst] @ wq1[r] against the L2-resident 92KB table, alpha = qi*kj,
// written back in place (linear, L2-hot). Phases C/D unchanged.
__global__ __launch_bounds__(256) void k_aggr1(const u16* relD, const int* rowptrD,
                                               const f16* hh, const float* wq1g,
                                               const f16* outj1h, float* alpha1s,
                                               const float* wmod, const float* bias1,
                                               f16* h1h) {
    __shared__ unsigned smax[4][RR * 5];
    __shared__ float    ssum[4][RR * 5];
    int wid = threadIdx.x >> 6;
    int lane = threadIdx.x & 63;
    int w = blockIdx.x * 4 + wid;       // grid = NN/4 exactly (NN % 4 == 0)
    int beg = rowptrD[w], end = rowptrD[w + 1];
    unsigned* mx = smax[wid];
    float*    sm = ssum[wid];
    // own dst feature row (128B, L2-hot)
    f16x8 hd[8];
#pragma unroll
    for (int cc = 0; cc < 8; ++cc)
        hd[cc] = *(const f16x8*)(hh + (size_t)w * 64 + cc * 8);
    for (int j = beg + lane; j < end; j += 64) {
        int rb = relD[j] * 5;
        mx[rb + 0] = ORD_NEGINF; mx[rb + 1] = ORD_NEGINF;
        mx[rb + 2] = ORD_NEGINF; mx[rb + 3] = ORD_NEGINF;
        sm[rb + 0] = 0.f; sm[rb + 1] = 0.f; sm[rb + 2] = 0.f; sm[rb + 3] = 0.f;
    }
    __syncthreads();
    // phase B: finish logit, write alpha back, LDS max
    for (int j = beg + lane; j < end; j += 64) {
        float4 kj = *(const float4*)(alpha1s + (size_t)j * 4);
        int r = relD[j];
        const float* qrow = wq1g + (size_t)r * 256;
        float q0 = 0.f, q1 = 0.f, q2 = 0.f, q3 = 0.f;
#pragma unroll
        for (int cc = 0; cc < 8; ++cc) {
#pragma unroll
            for (int jj = 0; jj < 8; ++jj) {
                float hv = (float)hd[cc][jj];
                const float* q4 = qrow + (cc * 8 + jj) * 4;
                q0 = fmaf(hv, q4[0], q0);
                q1 = fmaf(hv, q4[1], q1);
                q2 = fmaf(hv, q4[2], q2);
                q3 = fmaf(hv, q4[3], q3);
            }
        }
        float4 a;
        a.x = q0 * kj.x; a.y = q1 * kj.y; a.z = q2 * kj.z; a.w = q3 * kj.w;
        *(float4*)(alpha1s + (size_t)j * 4) = a;
        int rb = r * 5;
        atomicMax(&mx[rb + 0], f2ord(a.x));
        atomicMax(&mx[rb + 1], f2ord(a.y));
        atomicMax(&mx[rb + 2], f2ord(a.z));
        atomicMax(&mx[rb + 3], f2ord(a.w));
    }
    __syncthreads();
    for (int j = beg + lane; j < end; j += 64) {
        float4 a = *(const float4*)(alpha1s + (size_t)j * 4);
        int rb = relD[j] * 5;
        atomicAdd(&sm[rb + 0], __expf(a.x - ord2f(mx[rb + 0])));
        atomicAdd(&sm[rb + 1], __expf(a.y - ord2f(mx[rb + 1])));
        atomicAdd(&sm[rb + 2], __expf(a.z - ord2f(mx[rb + 2])));
        atomicAdd(&sm[rb + 3], __expf(a.w - ord2f(mx[rb + 3])));
    }
    __syncthreads();
    for (int t = lane; t < RR * 5; t += 64) sm[t] = 1.f / (sm[t] + EPS);
    __syncthreads();
    int hh2 = lane >= 20 ? 1 : 0;
    int oo = lane - hh2 * 20;
    float acc0 = 0.f, acc1 = 0.f, accw = 0.f;
    if (lane < 40) {
        for (int j = beg; j < end; ++j) {
            int rb = relD[j] * 5 + hh2 * 2;
            float v = (float)__builtin_nontemporal_load(outj1h + (size_t)j * 40 + lane);
            float2 a = *(const float2*)(alpha1s + (size_t)j * 4 + hh2 * 2);
            float e0 = __expf(a.x - ord2f(mx[rb]));
            float e1 = __expf(a.y - ord2f(mx[rb + 1]));
            acc0 = fmaf(v, e0 * sm[rb], acc0);
            acc1 = fmaf(v, e1 * sm[rb + 1], acc1);
            accw += v;
        }
        float wm = wmod[oo];
        int b0 = hh2 * 40 + oo;
        float o0 = fmaxf(acc0 + wm * accw + bias1[b0], 0.f);
        float o1 = fmaxf(acc1 + wm * accw + bias1[b0 + 20], 0.f);
        h1h[(size_t)w * 80 + b0]      = (f16)o0;
        h1h[(size_t)w * 80 + b0 + 20] = (f16)o1;
    }
}

// ---------------- conv2 fused: s-side logit + MFMA transform ----------------
// Stores (kj + ae) per edge (NO leaky-relu yet); qi + lrelu finished in
// k_aggr2. Only s-rows gathered. B-fragments read UNPADDED h1h[n][80].
__global__ __launch_bounds__(256) void k_c2(const int4* sortedR, const f16* h1h,
                                            const f16* w2hT, const float* wk2g,
                                            const float* aeS,
                                            float* alpha2s, f16* outj2h) {
    __shared__ float ks[4][160];
    int wid = threadIdx.x >> 6, l = threadIdx.x & 63;
    int wbase = blockIdx.x * 256 + wid * 64;
    int r = sortedR[wbase].z;
    float* kw = ks[wid];
    for (int t = l; t < 160; t += 64)
        kw[t] = wk2g[(size_t)r * 160 + t];
    __syncthreads();
    int row16 = l & 15, g = l >> 4;
    f16x8 a[2][2][2];   // [b][mt][kk]
#pragma unroll
    for (int b = 0; b < 2; ++b)
#pragma unroll
        for (int mt = 0; mt < 2; ++mt)
#pragma unroll
            for (int kk = 0; kk < 2; ++kk)
                a[b][mt][kk] = *(const f16x8*)(w2hT + ((((size_t)r * 2 + b) * 32) + mt * 16 + row16) * 64 + kk * 32 + g * 8);
    ivec4 er[3];
    f16x8 vb[3][2][2];   // [slot][b][kk]

#define C2_LOAD(SLOT, T) { \
    int e0_ = wbase + (T) * 16; \
    er[SLOT] = __builtin_nontemporal_load((const ivec4*)(sortedR + e0_ + row16)); \
    int s_ = er[SLOT][0]; \
    _Pragma("unroll") for (int b = 0; b < 2; ++b) \
        _Pragma("unroll") for (int kk = 0; kk < 2; ++kk) \
            vb[SLOT][b][kk] = *(const f16x8*)(h1h + (size_t)s_ * 80 + b * 40 + kk * 32 + g * 8); }

#define C2_COMP(SLOT, T) { \
    int pd_ = er[SLOT][3]; \
    float a0 = 0.f, a1 = 0.f; \
    _Pragma("unroll") for (int b = 0; b < 2; ++b) { \
        _Pragma("unroll") for (int j = 0; j < 8; ++j) { \
            int p = b * 40 + g * 8 + j; \
            float bv = (float)vb[SLOT][b][0][j]; \
            a0 = fmaf(bv, kw[p * 2 + 0], a0); \
            a1 = fmaf(bv, kw[p * 2 + 1], a1); } \
        if (g == 0) { \
            _Pragma("unroll") for (int j = 0; j < 8; ++j) { \
                int p = b * 40 + 32 + j; \
                float bv = (float)vb[SLOT][b][1][j]; \
                a0 = fmaf(bv, kw[p * 2 + 0], a0); \
                a1 = fmaf(bv, kw[p * 2 + 1], a1); } } } \
    a0 += __shfl_xor(a0, 16); a0 += __shfl_xor(a0, 32); \
    a1 += __shfl_xor(a1, 16); a1 += __shfl_xor(a1, 32); \
    f32x4 acc[2][2]; \
    _Pragma("unroll") for (int b = 0; b < 2; ++b) \
        _Pragma("unroll") for (int mt = 0; mt < 2; ++mt) acc[b][mt] = (f32x4){0.f,0.f,0.f,0.f}; \
    _Pragma("unroll") for (int b = 0; b < 2; ++b) \
        _Pragma("unroll") for (int mt = 0; mt < 2; ++mt) { \
            acc[b][mt] = __builtin_amdgcn_mfma_f32_16x16x32_f16(a[b][mt][0], vb[SLOT][b][0], acc[b][mt], 0, 0, 0); \
            acc[b][mt] = __builtin_amdgcn_mfma_f32_16x16x32_f16(a[b][mt][1], vb[SLOT][b][1], acc[b][mt], 0, 0, 0); } \
    if (pd_ >= 0) { \
        if (l < 16) { \
            float2 aev = *(const float2*)(aeS + (size_t)(wbase + (T) * 16 + row16) * 2); \
            float2 av; av.x = a0 + aev.x; av.y = a1 + aev.y; \
            *(float2*)(alpha2s + (size_t)pd_ * 2) = av; } \
        f16* orow = outj2h + (size_t)pd_ * 64; \
        _Pragma("unroll") for (int b = 0; b < 2; ++b) \
            _Pragma("unroll") for (int mt = 0; mt < 2; ++mt) { \
                f16x4 v; \
                v[0] = (f16)acc[b][mt][0]; v[1] = (f16)acc[b][mt][1]; \
                v[2] = (f16)acc[b][mt][2]; v[3] = (f16)acc[b][mt][3]; \
                *(f16x4*)(orow + b * 32 + mt * 16 + g * 4) = v; } } }

    C2_LOAD(0, 0)
    C2_LOAD(1, 1)
    C2_LOAD(2, 2)
    C2_COMP(0, 0)
    C2_LOAD(0, 3)
    C2_COMP(1, 1)
    C2_COMP(2, 2)
    C2_COMP(0, 3)
#undef C2_LOAD
#undef C2_COMP
}

// ---------------- conv2 aggregate + dst-side logit + softmax ----------------
// alpha2s holds (kj + ae); phase B adds qi = h1[dst] @ wq2[r] (L2-resident
// 57KB table), applies leaky-relu, writes alpha back. NN % 4 == 0 -> no
// early return, barriers safe.
__global__ __launch_bounds__(256) void k_aggr2(const u16* relD, const int* rowptrD,
                                               const f16* h1h, const float* wq2g,
                                               const f16* outj2h, float* alpha2s,
                                               float* h2) {
    int w = blockIdx.x * 4 + (threadIdx.x >> 6);
    int lane = threadIdx.x & 63;
    int beg = rowptrD[w], end = rowptrD[w + 1];
    // own dst feature row (160B, L2-hot)
    f16x8 hd[10];
#pragma unroll
    for (int cc = 0; cc < 10; ++cc)
        hd[cc] = *(const f16x8*)(h1h + (size_t)w * 80 + cc * 8);
    // phase B: finish logit + lrelu, write back, track max
    float m0 = -INFINITY, m1 = -INFINITY;
    for (int j = beg + lane; j < end; j += 64) {
        float2 kv = *(const float2*)(alpha2s + (size_t)j * 2);
        int r = relD[j];
        const float* qrow = wq2g + (size_t)r * 160;
        float q0 = 0.f, q1 = 0.f;
#pragma unroll
        for (int cc = 0; cc < 10; ++cc) {
#pragma unroll
            for (int jj = 0; jj < 8; ++jj) {
                float hv = (float)hd[cc][jj];
                int p = cc * 8 + jj;
                q0 = fmaf(hv, qrow[p * 2 + 0], q0);
                q1 = fmaf(hv, qrow[p * 2 + 1], q1);
            }
        }
        float x0 = q0 + kv.x, x1 = q1 + kv.y;
        x0 = x0 > 0.f ? x0 : 0.2f * x0;
        x1 = x1 > 0.f ? x1 : 0.2f * x1;
        float2 av; av.x = x0; av.y = x1;
        *(float2*)(alpha2s + (size_t)j * 2) = av;
        m0 = fmaxf(m0, x0); m1 = fmaxf(m1, x1);
    }
#pragma unroll
    for (int off = 32; off; off >>= 1) {
        m0 = fmaxf(m0, __shfl_xor(m0, off));
        m1 = fmaxf(m1, __shfl_xor(m1, off));
    }
    __syncthreads();   // write-backs visible for cross-lane phase D reads
    float s0 = 0.f, s1 = 0.f;
    for (int j = beg + lane; j < end; j += 64) {
        float2 a = *(const float2*)(alpha2s + (size_t)j * 2);
        s0 += __expf(a.x - m0); s1 += __expf(a.y - m1);
    }
#pragma unroll
    for (int off = 32; off; off >>= 1) {
        s0 += __shfl_xor(s0, off);
        s1 += __shfl_xor(s1, off);
    }
    int b = lane >> 5;
    float mb = b ? m1 : m0;
    float rs = 1.f / ((b ? s1 : s0) + EPS);
    float acc = 0.f;
    for (int j = beg; j < end; ++j) {
        float v = (float)__builtin_nontemporal_load(outj2h + (size_t)j * 64 + lane);
        float a = alpha2s[(size_t)j * 2 + b];
        acc = fmaf(v, __expf(a - mb) * rs, acc);
    }
    h2[(size_t)w * 64 + lane] = acc;
}

__global__ void k_out(const float* h2, const float* lin2_w, const float* lin2_b,
                      float* out) {
    int n = blockIdx.x * blockDim.x + threadIdx.x;
    if (n >= NN) return;
    float o[4] = {lin2_b[0], lin2_b[1], lin2_b[2], lin2_b[3]};
    const float* hr = h2 + (size_t)n * 64;
    for (int c = 0; c < 64; ++c) {
        float hv = hr[c];
#pragma unroll
        for (int t = 0; t < 4; ++t) o[t] = fmaf(hv, lin2_w[c * 4 + t], o[t]);
    }
    float m = fmaxf(fmaxf(o[0], o[1]), fmaxf(o[2], o[3]));
    float s = __expf(o[0] - m) + __expf(o[1] - m) + __expf(o[2] - m) + __expf(o[3] - m);
    float lse = m + logf(s);
#pragma unroll
    for (int t = 0; t < 4; ++t) out[(size_t)n * 4 + t] = o[t] - lse;
}

extern "C" void kernel_launch(void* const* d_in, const int* in_sizes, int n_in,
                              void* d_out, int out_size, void* d_ws, size_t ws_size,
                              hipStream_t stream) {
    const float* x        = (const float*)d_in[0];
    const int*   eidx     = (const int*)d_in[1];
    const int*   etype    = (const int*)d_in[2];
    const float* eattr    = (const float*)d_in[3];
    const float* lin1_w   = (const float*)d_in[4];
    const float* att1     = (const float*)d_in[5];
    const float* basis1   = (const float*)d_in[6];
    const float* q1       = (const float*)d_in[7];
    const float* k1       = (const float*)d_in[8];
    const float* wmod1    = (const float*)d_in[9];
    const float* bias1    = (const float*)d_in[10];
    const float* w2       = (const float*)d_in[11];
    const float* q2       = (const float*)d_in[12];
    const float* k2       = (const float*)d_in[13];
    const float* lew      = (const float*)d_in[14];
    const float* e2i      = (const float*)d_in[15];
    const float* lin2_w   = (const float*)d_in[16];
    const float* lin2_b   = (const float*)d_in[17];

    const int* src = eidx;
    const int* dst = eidx + EE;

    // ---------------- workspace layout (f32 units) ----------------
    float* W = (float*)d_ws;
    float* w1      = W;   W += 230400;
    float* wq1     = W;   W += 23040;
    float* wk1     = W;   W += 23040;
    float* wq2     = W;   W += 14400;
    float* wk2     = W;   W += 14400;
    float* we      = W;   W += 32;
    float* h2      = W;   W += (size_t)NN * 64;
    float* aeS     = W;   W += (size_t)E2 * 2;
    f16*   hh      = (f16*)W;   W += (size_t)NN * 64 / 2;        // N*64 f16 (logits+MFMA)
    f16*   h1h     = (f16*)W;   W += (size_t)NN * 80 / 2 + 32;   // N*80 f16 + 64-elem pad
    f16*   w1hT    = (f16*)W;   W += (size_t)RR * 48 * 64 / 2;
    f16*   w2hT    = (f16*)W;   W += (size_t)RR * 2 * 32 * 64 / 2;
    // union region: conv1 {outj1h[EE*40 f16], alpha1s[EE*4 f32]} / conv2 {outj2h[EE*64 f16]}
    float* uni     = W;   W += (size_t)EE * 20 + (size_t)EE * 4;  // 24 f32-units/edge
    f16*   outj1h  = (f16*)uni;
    float* alpha1s = uni + (size_t)EE * 20;
    f16*   outj2h  = (f16*)uni;
    W += (size_t)EE * 8;                   // extend union to EE*32 f32 for outj2h
    float* alpha2s = W;   W += (size_t)EE * 2;
    int4*  sortedR = (int4*)W;
    int*   I = (int*)W;   I += (size_t)E2 * 4;
    u16*   relD    = (u16*)I;   I += (size_t)E2 / 2;
    int*   posS    = I;   I += EE;
    int*   rowptrD = I;   I += NN + 1;
    int*   cursorD = I;   I += NN;
    int*   histD   = I;   I += NN;    // zeroed block starts here
    int*   hist    = I;   I += 128;
    int*   cursor  = I;   I += 128;

    // ---------------- init ----------------
    hipMemsetAsync(histD, 0, (size_t)(NN + 256) * 4, stream);
    hipMemsetAsync(h1h + (size_t)NN * 80, 0, 128, stream);  // zero K-pad tail
    k_fillrec<<<E2 / 256, 256, 0, stream>>>(sortedR, E2);

    // sorts
    k_hist<<<EE / 256, 256, 0, stream>>>(etype, hist);
    k_scanPad<<<1, 64, 0, stream>>>(hist, cursor);
    k_scatter<<<EE / 256, 256, 0, stream>>>(src, dst, etype, cursor, sortedR, posS);
    k_histD<<<EE / 256, 256, 0, stream>>>(dst, histD);
    k_scanD<<<1, 256, 0, stream>>>(histD, rowptrD, cursorD);
    k_scatterD<<<E2 / 256, 256, 0, stream>>>(sortedR, cursorD, relD);

    // folded weights + f16 prep + dense input layer + edge-attr logits
    k_w1<<<(RR * 2560 + 255) / 256, 256, 0, stream>>>(att1, basis1, w1);
    k_wqk1<<<(RR * 256 + 255) / 256, 256, 0, stream>>>(w1, q1, k1, wq1, wk1);
    k_wqk2<<<(RR * 160 + 255) / 256, 256, 0, stream>>>(w2, q2, k2, wq2, wk2);
    k_we<<<1, 32, 0, stream>>>(lew, e2i, we);
    k_ae<<<EE / 256, 256, 0, stream>>>(eattr, we, posS, aeS);
    k_w1hT<<<(RR * 48 * 64) / 256, 256, 0, stream>>>(w1, w1hT);
    k_w2hT<<<(RR * 2 * 32 * 64) / 256, 256, 0, stream>>>(w2, w2hT);
    k_h<<<NN, 64, 0, stream>>>(x, lin1_w, hh);

    // conv1 (s-side logits + transform; dst-side finished in aggr1)
    k_c1<<<E2 / 256, 256, 0, stream>>>(sortedR, hh, w1hT, wk1, alpha1s, outj1h);
    k_aggr1<<<NN / 4, 256, 0, stream>>>(relD, rowptrD, hh, wq1, outj1h, alpha1s,
                                        wmod1, bias1, h1h);

    // conv2 (s-side logits + transform; dst-side finished in aggr2)
    k_c2<<<E2 / 256, 256, 0, stream>>>(sortedR, h1h, w2hT, wk2, aeS,
                                       alpha2s, outj2h);
    k_aggr2<<<NN / 4, 256, 0, stream>>>(relD, rowptrD, h1h, wq2, outj2h,
                                        alpha2s, h2);

    k_out<<<(NN + 255) / 256, 256, 0, stream>>>(h2, lin2_w, lin2_b, (float*)d_out);
}

// Round 13
// 585.069 us; speedup vs baseline: 1.6371x; 1.6371x over previous
//
#include <hip/hip_runtime.h>
#include <math.h>

constexpr int NN   = 20000;   // nodes
constexpr int EE   = 640000;  // edges
constexpr int RR   = 90;      // relations
constexpr int INF_ = 128;     // in features
constexpr int HID  = 64;      // hidden
constexpr float EPS = 1e-16f;
constexpr int E2   = 646144;  // padded edge capacity: 2524*256, >= EE + 90*63

typedef unsigned short u16;
typedef _Float16 f16;
typedef __attribute__((ext_vector_type(8))) _Float16 f16x8;
typedef __attribute__((ext_vector_type(4))) _Float16 f16x4;
typedef __attribute__((ext_vector_type(4))) float f32x4;
typedef __attribute__((ext_vector_type(4))) int ivec4;
typedef __attribute__((ext_vector_type(2))) float fvec2;

// order-preserving float<->uint encode (monotone: f<g  <=>  f2ord(f)<f2ord(g))
__device__ inline unsigned f2ord(float f) {
    unsigned u = __float_as_uint(f);
    return (u & 0x80000000u) ? ~u : (u | 0x80000000u);
}
__device__ inline float ord2f(unsigned x) {
    unsigned u = (x & 0x80000000u) ? (x & 0x7FFFFFFFu) : ~x;
    return __uint_as_float(u);
}
// f2ord(-INF) = 0x007FFFFF — table init value
#define ORD_NEGINF 0x007FFFFFu

__global__ void k_fillrec(int4* p, int n) {
    int i = blockIdx.x * blockDim.x + threadIdx.x;
    if (i < n) { int4 r; r.x = 0; r.y = 0; r.z = 0; r.w = -1; p[i] = r; }
}

// ---------------- sort 1: by relation, segment-padded to 64 ----------------
__global__ void k_hist(const int* et, int* hist) {
    __shared__ int lh[RR];
    if (threadIdx.x < RR) lh[threadIdx.x] = 0;
    __syncthreads();
    int i = blockIdx.x * blockDim.x + threadIdx.x;
    if (i < EE) atomicAdd(&lh[et[i]], 1);
    __syncthreads();
    if (threadIdx.x < RR) atomicAdd(&hist[threadIdx.x], lh[threadIdx.x]);
}

__global__ void k_scanPad(const int* hist, int* cursor) {
    if (threadIdx.x == 0) {
        int acc = 0;
        for (int r = 0; r < RR; ++r) {
            cursor[r] = acc;
            acc += (hist[r] + 63) & ~63;   // pad each segment to 64
        }
    }
}

// sortedR records {src, dst, rel, orig}; dummies stay {0,0,0,-1}
// posS[orig] = relation-sorted position (for sorted ae scatter)
__global__ void k_scatter(const int* src, const int* dst, const int* et,
                          int* cursor, int4* sortedR, int* posS) {
    __shared__ int lh[RR];
    __shared__ int lbase[RR];
    if (threadIdx.x < RR) lh[threadIdx.x] = 0;
    __syncthreads();
    int i = blockIdx.x * blockDim.x + threadIdx.x;
    int r = et[i];
    int rank = atomicAdd(&lh[r], 1);
    __syncthreads();
    if (threadIdx.x < RR) {
        int c = lh[threadIdx.x];
        lbase[threadIdx.x] = c ? atomicAdd(&cursor[threadIdx.x], c) : 0;
    }
    __syncthreads();
    int pos = lbase[r] + rank;
    int4 rec; rec.x = src[i]; rec.y = dst[i]; rec.z = r; rec.w = i;
    sortedR[pos] = rec;
    posS[i] = pos;
}

// ---------------- sort 2: by destination ----------------
__global__ void k_histD(const int* dst, int* histD) {
    int i = blockIdx.x * blockDim.x + threadIdx.x;
    if (i < EE) atomicAdd(&histD[dst[i]], 1);
}

__global__ void k_scanD(const int* histD, int* rowptrD, int* cursorD) {
    __shared__ int part[256];
    const int CH = (NN + 255) / 256;
    int tid = threadIdx.x;
    int base = tid * CH;
    int s = 0;
    for (int j = 0; j < CH; ++j) {
        int idx = base + j;
        if (idx < NN) s += histD[idx];
    }
    part[tid] = s;
    __syncthreads();
    if (tid == 0) {
        int acc = 0;
        for (int t = 0; t < 256; ++t) { int v = part[t]; part[t] = acc; acc += v; }
    }
    __syncthreads();
    int acc = part[tid];
    for (int j = 0; j < CH; ++j) {
        int idx = base + j;
        if (idx < NN) {
            rowptrD[idx] = acc;
            cursorD[idx] = acc;
            acc += histD[idx];
        }
    }
    if (tid == 0) rowptrD[NN] = EE;
}

// rewrites sortedR[i].w = dst-sorted position (dummies keep -1);
// relD[dstpos] = relation (u16)
__global__ void k_scatterD(int4* sortedR, int* cursorD, u16* relD) {
    int i = blockIdx.x * blockDim.x + threadIdx.x;
    if (i >= E2) return;
    int4 rec = sortedR[i];
    if (rec.w < 0) return;
    int pos = atomicAdd(&cursorD[rec.y], 1);
    ((int*)(sortedR + i))[3] = pos;
    relD[pos] = (u16)rec.z;
}

// ---------------- weight folding ----------------
__global__ void k_w1(const float* att1, const float* basis1, float* w1) {
    int idx = blockIdx.x * blockDim.x + threadIdx.x;
    if (idx >= RR * 2560) return;
    int r = idx / 2560, co = idx - r * 2560;
    float acc = 0.f;
    for (int b = 0; b < 35; ++b) acc += att1[r * 35 + b] * basis1[b * 2560 + co];
    w1[idx] = acc;
}

__global__ void k_wqk1(const float* w1, const float* q1, const float* k1,
                       float* wq1, float* wk1) {
    int idx = blockIdx.x * blockDim.x + threadIdx.x;
    if (idx >= RR * 64 * 4) return;
    int t = idx & 3, c = (idx >> 2) & 63, r = idx >> 8;
    const float* wrow = w1 + (size_t)r * 2560 + c * 40;
    float aq = 0.f, ak = 0.f;
    for (int o = 0; o < 40; ++o) {
        float w = wrow[o];
        aq += w * q1[o * 4 + t];
        ak += w * k1[o * 4 + t];
    }
    wq1[idx] = aq; wk1[idx] = ak;
}

__global__ void k_wqk2(const float* w2, const float* q2, const float* k2,
                       float* wq2, float* wk2) {
    int idx = blockIdx.x * blockDim.x + threadIdx.x;
    if (idx >= RR * 80 * 2) return;
    int t = idx & 1, bc = (idx >> 1) % 80, r = idx / 160;
    int b = bc / 40, c = bc % 40;
    const float* wbase = w2 + (size_t)((r * 2 + b) * 40 + c) * 32;
    float aq = 0.f, ak = 0.f;
    for (int d = 0; d < 32; ++d) {
        float w = wbase[d];
        aq += w * q2[(b * 32 + d) * 2 + t];
        ak += w * k2[(b * 32 + d) * 2 + t];
    }
    wq2[idx] = aq; wk2[idx] = ak;
}

__global__ void k_we(const float* lew, const float* e2, float* we) {
    int idx = threadIdx.x;
    if (idx >= 32) return;
    int i = idx >> 1, t = idx & 1;
    float acc = 0.f;
    for (int j = 0; j < 64; ++j) acc += lew[i * 64 + j] * e2[j * 2 + t];
    we[idx] = acc;
}

// aeS[posS[e]][2] = edge_attr[e] @ we  — coalesced read, scattered 8B write
__global__ __launch_bounds__(256) void k_ae(const float* ea, const float* weg,
                                            const int* posS, float* aeS) {
    __shared__ float wes[32];
    if (threadIdx.x < 32) wes[threadIdx.x] = weg[threadIdx.x];
    __syncthreads();
    int e = blockIdx.x * 256 + threadIdx.x;
    if (e >= EE) return;
    const float4* ep = (const float4*)(ea + (size_t)e * 16);
    float a0 = 0.f, a1 = 0.f;
#pragma unroll
    for (int cc = 0; cc < 4; ++cc) {
        float4 v = ep[cc];
        const float* vv = (const float*)&v;
#pragma unroll
        for (int j = 0; j < 4; ++j) {
            int ii = cc * 4 + j;
            a0 = fmaf(vv[j], wes[ii * 2 + 0], a0);
            a1 = fmaf(vv[j], wes[ii * 2 + 1], a1);
        }
    }
    float2 av; av.x = a0; av.y = a1;
    *(float2*)(aeS + (size_t)posS[e] * 2) = av;
}

// f16 transposed+padded weights: w1hT[r][o(48)][k(64)]
__global__ void k_w1hT(const float* w1, f16* w1hT) {
    int idx = blockIdx.x * blockDim.x + threadIdx.x;
    if (idx >= RR * 48 * 64) return;
    int k = idx & 63, o = (idx >> 6) % 48, r = idx / (48 * 64);
    float v = (o < 40) ? w1[(size_t)r * 2560 + k * 40 + o] : 0.f;
    w1hT[idx] = (f16)v;
}

// w2hT[r][b][d(32)][c(64)]  (c = K, padded 40->64 with ZEROS — enables
// unpadded h1h B-fragment reads: garbage at K>=40 multiplies zero)
__global__ void k_w2hT(const float* w2, f16* w2hT) {
    int idx = blockIdx.x * blockDim.x + threadIdx.x;
    if (idx >= RR * 2 * 32 * 64) return;
    int c = idx & 63, d = (idx >> 6) & 31, b = (idx >> 11) & 1, r = idx >> 12;
    float v = (c < 40) ? w2[((((size_t)r * 2 + b) * 40) + c) * 32 + d] : 0.f;
    w2hT[idx] = (f16)v;
}

// hh = f16(x @ lin1_w) — single buffer for logits AND MFMA B-operand
__global__ void k_h(const float* x, const float* lin1_w, f16* hh) {
    __shared__ float xs[INF_];
    int n = blockIdx.x, t = threadIdx.x;
    xs[t]      = x[(size_t)n * INF_ + t];
    xs[t + 64] = x[(size_t)n * INF_ + t + 64];
    __syncthreads();
    float acc = 0.f;
    for (int i = 0; i < INF_; ++i) acc += xs[i] * lin1_w[i * HID + t];
    hh[(size_t)n * HID + t] = (f16)acc;
}

// ---------------- conv1 fused: logits + MFMA transform ----------------------
// Each wave owns 64 consecutive edges (rel-uniform by 64-padding), processed
// as 4 groups of 16 with a depth-2 software pipeline (2 gather-groups in
// flight). Weights + qs/ks loaded once per 64 edges. nt loads on sortedR.
__global__ __launch_bounds__(256) void k_c1(const int4* sortedR, const f16* hh,
                                            const f16* w1hT,
                                            const float* wq1g, const float* wk1g,
                                            float* alpha1s, f16* outj1h) {
    __shared__ float qs[4][256], ks[4][256];
    int wid = threadIdx.x >> 6, l = threadIdx.x & 63;
    int wbase = blockIdx.x * 256 + wid * 64;
    int r = sortedR[wbase].z;
    float* qw = qs[wid];
    float* kw = ks[wid];
    for (int t = l; t < 256; t += 64) {
        qw[t] = wq1g[(size_t)r * 256 + t];
        kw[t] = wk1g[(size_t)r * 256 + t];
    }
    __syncthreads();
    int row16 = l & 15, g = l >> 4;
    f16x8 a[3][2];
#pragma unroll
    for (int mt = 0; mt < 3; ++mt)
#pragma unroll
        for (int kk = 0; kk < 2; ++kk)
            a[mt][kk] = *(const f16x8*)(w1hT + ((size_t)r * 48 + mt * 16 + row16) * 64 + kk * 32 + g * 8);
    ivec4 er[2];
    f16x8 vb0[2], vb1[2], vd0[2], vd1[2];

#define C1_LOAD(SLOT, T) { \
    int e0_ = wbase + (T) * 16; \
    er[SLOT] = __builtin_nontemporal_load((const ivec4*)(sortedR + e0_ + row16)); \
    int s_ = er[SLOT][0], d_ = er[SLOT][1]; \
    vb0[SLOT] = *(const f16x8*)(hh + (size_t)s_ * 64 + g * 8); \
    vb1[SLOT] = *(const f16x8*)(hh + (size_t)s_ * 64 + 32 + g * 8); \
    vd0[SLOT] = *(const f16x8*)(hh + (size_t)d_ * 64 + g * 8); \
    vd1[SLOT] = *(const f16x8*)(hh + (size_t)d_ * 64 + 32 + g * 8); }

#define C1_COMP(SLOT) { \
    int pd_ = er[SLOT][3]; \
    float qi[4] = {0.f,0.f,0.f,0.f}, kj[4] = {0.f,0.f,0.f,0.f}; \
    _Pragma("unroll") for (int j = 0; j < 8; ++j) { \
        int p0 = g * 8 + j, p1 = 32 + g * 8 + j; \
        float dv0 = (float)vd0[SLOT][j], dv1 = (float)vd1[SLOT][j]; \
        float bv0 = (float)vb0[SLOT][j], bv1 = (float)vb1[SLOT][j]; \
        _Pragma("unroll") for (int t2 = 0; t2 < 4; ++t2) { \
            qi[t2] = fmaf(dv0, qw[p0 * 4 + t2], fmaf(dv1, qw[p1 * 4 + t2], qi[t2])); \
            kj[t2] = fmaf(bv0, kw[p0 * 4 + t2], fmaf(bv1, kw[p1 * 4 + t2], kj[t2])); } } \
    _Pragma("unroll") for (int t2 = 0; t2 < 4; ++t2) { \
        qi[t2] += __shfl_xor(qi[t2], 16); qi[t2] += __shfl_xor(qi[t2], 32); \
        kj[t2] += __shfl_xor(kj[t2], 16); kj[t2] += __shfl_xor(kj[t2], 32); } \
    f32x4 acc[3]; \
    _Pragma("unroll") for (int mt = 0; mt < 3; ++mt) acc[mt] = (f32x4){0.f,0.f,0.f,0.f}; \
    _Pragma("unroll") for (int mt = 0; mt < 3; ++mt) { \
        acc[mt] = __builtin_amdgcn_mfma_f32_16x16x32_f16(a[mt][0], vb0[SLOT], acc[mt], 0, 0, 0); \
        acc[mt] = __builtin_amdgcn_mfma_f32_16x16x32_f16(a[mt][1], vb1[SLOT], acc[mt], 0, 0, 0); } \
    if (pd_ >= 0) { \
        if (l < 16) { \
            float4 av; \
            av.x = qi[0] * kj[0]; av.y = qi[1] * kj[1]; \
            av.z = qi[2] * kj[2]; av.w = qi[3] * kj[3]; \
            *(float4*)(alpha1s + (size_t)pd_ * 4) = av; } \
        f16* orow = outj1h + (size_t)pd_ * 40; \
        _Pragma("unroll") for (int mt = 0; mt < 3; ++mt) { \
            int col = mt * 16 + g * 4; \
            if (col < 40) { \
                f16x4 v; \
                v[0] = (f16)acc[mt][0]; v[1] = (f16)acc[mt][1]; \
                v[2] = (f16)acc[mt][2]; v[3] = (f16)acc[mt][3]; \
                *(f16x4*)(orow + col) = v; } } } }

    C1_LOAD(0, 0)
    C1_LOAD(1, 1)
    C1_COMP(0)
    C1_LOAD(0, 2)
    C1_COMP(1)
    C1_LOAD(1, 3)
    C1_COMP(0)
    C1_COMP(1)
#undef C1_LOAD
#undef C1_COMP
}

// ---------------- conv1 aggregate + wave-local segment softmax ----------------
__global__ __launch_bounds__(256) void k_aggr1(const u16* relD, const int* rowptrD,
                                               const f16* outj1h, const float* alpha1s,
                                               const float* wmod, const float* bias1,
                                               f16* h1h) {
    __shared__ unsigned smax[4][RR * 5];
    __shared__ float    ssum[4][RR * 5];
    int wid = threadIdx.x >> 6;
    int lane = threadIdx.x & 63;
    int w = blockIdx.x * 4 + wid;       // grid = NN/4 exactly (NN % 4 == 0)
    int beg = rowptrD[w], end = rowptrD[w + 1];
    unsigned* mx = smax[wid];
    float*    sm = ssum[wid];
    for (int j = beg + lane; j < end; j += 64) {
        int rb = relD[j] * 5;
        mx[rb + 0] = ORD_NEGINF; mx[rb + 1] = ORD_NEGINF;
        mx[rb + 2] = ORD_NEGINF; mx[rb + 3] = ORD_NEGINF;
        sm[rb + 0] = 0.f; sm[rb + 1] = 0.f; sm[rb + 2] = 0.f; sm[rb + 3] = 0.f;
    }
    __syncthreads();
    for (int j = beg + lane; j < end; j += 64) {
        float4 a = *(const float4*)(alpha1s + (size_t)j * 4);
        int rb = relD[j] * 5;
        atomicMax(&mx[rb + 0], f2ord(a.x));
        atomicMax(&mx[rb + 1], f2ord(a.y));
        atomicMax(&mx[rb + 2], f2ord(a.z));
        atomicMax(&mx[rb + 3], f2ord(a.w));
    }
    __syncthreads();
    for (int j = beg + lane; j < end; j += 64) {
        float4 a = *(const float4*)(alpha1s + (size_t)j * 4);
        int rb = relD[j] * 5;
        atomicAdd(&sm[rb + 0], __expf(a.x - ord2f(mx[rb + 0])));
        atomicAdd(&sm[rb + 1], __expf(a.y - ord2f(mx[rb + 1])));
        atomicAdd(&sm[rb + 2], __expf(a.z - ord2f(mx[rb + 2])));
        atomicAdd(&sm[rb + 3], __expf(a.w - ord2f(mx[rb + 3])));
    }
    __syncthreads();
    for (int t = lane; t < RR * 5; t += 64) sm[t] = 1.f / (sm[t] + EPS);
    __syncthreads();
    int hh2 = lane >= 20 ? 1 : 0;
    int oo = lane - hh2 * 20;
    float acc0 = 0.f, acc1 = 0.f, accw = 0.f;
    if (lane < 40) {
        for (int j = beg; j < end; ++j) {
            int rb = relD[j] * 5 + hh2 * 2;
            float v = (float)__builtin_nontemporal_load(outj1h + (size_t)j * 40 + lane);
            float2 a = *(const float2*)(alpha1s + (size_t)j * 4 + hh2 * 2);
            float e0 = __expf(a.x - ord2f(mx[rb]));
            float e1 = __expf(a.y - ord2f(mx[rb + 1]));
            acc0 = fmaf(v, e0 * sm[rb], acc0);
            acc1 = fmaf(v, e1 * sm[rb + 1], acc1);
            accw += v;
        }
        float wm = wmod[oo];
        int b0 = hh2 * 40 + oo;
        float o0 = fmaxf(acc0 + wm * accw + bias1[b0], 0.f);
        float o1 = fmaxf(acc1 + wm * accw + bias1[b0 + 20], 0.f);
        h1h[(size_t)w * 80 + b0]      = (f16)o0;
        h1h[(size_t)w * 80 + b0 + 20] = (f16)o1;
    }
}

// ---------------- conv2 fused: logits + MFMA transform ----------------------
// Same 64-edges-per-wave depth-2 pipeline. B-fragments read UNPADDED
// h1h[n][80]; K>=40 garbage multiplies zero weights. aeS read non-temporal
// (single-use linear stream).
__global__ __launch_bounds__(256) void k_c2(const int4* sortedR, const f16* h1h,
                                            const f16* w2hT,
                                            const float* wq2g, const float* wk2g,
                                            const float* aeS,
                                            float* alpha2s, f16* outj2h) {
    __shared__ float qs[4][160], ks[4][160];
    int wid = threadIdx.x >> 6, l = threadIdx.x & 63;
    int wbase = blockIdx.x * 256 + wid * 64;
    int r = sortedR[wbase].z;
    float* qw = qs[wid];
    float* kw = ks[wid];
    for (int t = l; t < 160; t += 64) {
        qw[t] = wq2g[(size_t)r * 160 + t];
        kw[t] = wk2g[(size_t)r * 160 + t];
    }
    __syncthreads();
    int row16 = l & 15, g = l >> 4;
    f16x8 a[2][2][2];   // [b][mt][kk]
#pragma unroll
    for (int b = 0; b < 2; ++b)
#pragma unroll
        for (int mt = 0; mt < 2; ++mt)
#pragma unroll
            for (int kk = 0; kk < 2; ++kk)
                a[b][mt][kk] = *(const f16x8*)(w2hT + ((((size_t)r * 2 + b) * 32) + mt * 16 + row16) * 64 + kk * 32 + g * 8);
    ivec4 er[2];
    f16x8 vb[2][2][2], vd[2][2][2];   // [slot][b][kk]

#define C2_LOAD(SLOT, T) { \
    int e0_ = wbase + (T) * 16; \
    er[SLOT] = __builtin_nontemporal_load((const ivec4*)(sortedR + e0_ + row16)); \
    int s_ = er[SLOT][0], d_ = er[SLOT][1]; \
    _Pragma("unroll") for (int b = 0; b < 2; ++b) \
        _Pragma("unroll") for (int kk = 0; kk < 2; ++kk) { \
            vb[SLOT][b][kk] = *(const f16x8*)(h1h + (size_t)s_ * 80 + b * 40 + kk * 32 + g * 8); \
            vd[SLOT][b][kk] = *(const f16x8*)(h1h + (size_t)d_ * 80 + b * 40 + kk * 32 + g * 8); } }

#define C2_COMP(SLOT, T) { \
    int pd_ = er[SLOT][3]; \
    float a0 = 0.f, a1 = 0.f; \
    _Pragma("unroll") for (int b = 0; b < 2; ++b) { \
        _Pragma("unroll") for (int j = 0; j < 8; ++j) { \
            int p = b * 40 + g * 8 + j; \
            float dv = (float)vd[SLOT][b][0][j], bv = (float)vb[SLOT][b][0][j]; \
            a0 = fmaf(dv, qw[p * 2 + 0], fmaf(bv, kw[p * 2 + 0], a0)); \
            a1 = fmaf(dv, qw[p * 2 + 1], fmaf(bv, kw[p * 2 + 1], a1)); } \
        if (g == 0) { \
            _Pragma("unroll") for (int j = 0; j < 8; ++j) { \
                int p = b * 40 + 32 + j; \
                float dv = (float)vd[SLOT][b][1][j], bv = (float)vb[SLOT][b][1][j]; \
                a0 = fmaf(dv, qw[p * 2 + 0], fmaf(bv, kw[p * 2 + 0], a0)); \
                a1 = fmaf(dv, qw[p * 2 + 1], fmaf(bv, kw[p * 2 + 1], a1)); } } } \
    a0 += __shfl_xor(a0, 16); a0 += __shfl_xor(a0, 32); \
    a1 += __shfl_xor(a1, 16); a1 += __shfl_xor(a1, 32); \
    f32x4 acc[2][2]; \
    _Pragma("unroll") for (int b = 0; b < 2; ++b) \
        _Pragma("unroll") for (int mt = 0; mt < 2; ++mt) acc[b][mt] = (f32x4){0.f,0.f,0.f,0.f}; \
    _Pragma("unroll") for (int b = 0; b < 2; ++b) \
        _Pragma("unroll") for (int mt = 0; mt < 2; ++mt) { \
            acc[b][mt] = __builtin_amdgcn_mfma_f32_16x16x32_f16(a[b][mt][0], vb[SLOT][b][0], acc[b][mt], 0, 0, 0); \
            acc[b][mt] = __builtin_amdgcn_mfma_f32_16x16x32_f16(a[b][mt][1], vb[SLOT][b][1], acc[b][mt], 0, 0, 0); } \
    if (pd_ >= 0) { \
        if (l < 16) { \
            fvec2 aev = __builtin_nontemporal_load((const fvec2*)(aeS + (size_t)(wbase + (T) * 16 + row16) * 2)); \
            float x0 = a0 + aev[0], x1 = a1 + aev[1]; \
            x0 = x0 > 0.f ? x0 : 0.2f * x0; \
            x1 = x1 > 0.f ? x1 : 0.2f * x1; \
            float2 av; av.x = x0; av.y = x1; \
            *(float2*)(alpha2s + (size_t)pd_ * 2) = av; } \
        f16* orow = outj2h + (size_t)pd_ * 64; \
        _Pragma("unroll") for (int b = 0; b < 2; ++b) \
            _Pragma("unroll") for (int mt = 0; mt < 2; ++mt) { \
                f16x4 v; \
                v[0] = (f16)acc[b][mt][0]; v[1] = (f16)acc[b][mt][1]; \
                v[2] = (f16)acc[b][mt][2]; v[3] = (f16)acc[b][mt][3]; \
                *(f16x4*)(orow + b * 32 + mt * 16 + g * 4) = v; } } }

    C2_LOAD(0, 0)
    C2_LOAD(1, 1)
    C2_COMP(0, 0)
    C2_LOAD(0, 2)
    C2_COMP(1, 1)
    C2_LOAD(1, 3)
    C2_COMP(0, 2)
    C2_COMP(1, 3)
#undef C2_LOAD
#undef C2_COMP
}

// ---------------- conv2 aggregate + wave-local softmax (per-dst segments) ----
__global__ __launch_bounds__(256) void k_aggr2(const int* rowptrD, const f16* outj2h,
                                               const float* alpha2s, float* h2) {
    int w = blockIdx.x * 4 + (threadIdx.x >> 6);
    int lane = threadIdx.x & 63;
    if (w >= NN) return;
    int beg = rowptrD[w], end = rowptrD[w + 1];
    float m0 = -INFINITY, m1 = -INFINITY;
    for (int j = beg + lane; j < end; j += 64) {
        float2 a = *(const float2*)(alpha2s + (size_t)j * 2);
        m0 = fmaxf(m0, a.x); m1 = fmaxf(m1, a.y);
    }
#pragma unroll
    for (int off = 32; off; off >>= 1) {
        m0 = fmaxf(m0, __shfl_xor(m0, off));
        m1 = fmaxf(m1, __shfl_xor(m1, off));
    }
    float s0 = 0.f, s1 = 0.f;
    for (int j = beg + lane; j < end; j += 64) {
        float2 a = *(const float2*)(alpha2s + (size_t)j * 2);
        s0 += __expf(a.x - m0); s1 += __expf(a.y - m1);
    }
#pragma unroll
    for (int off = 32; off; off >>= 1) {
        s0 += __shfl_xor(s0, off);
        s1 += __shfl_xor(s1, off);
    }
    int b = lane >> 5;
    float mb = b ? m1 : m0;
    float rs = 1.f / ((b ? s1 : s0) + EPS);
    float acc = 0.f;
    for (int j = beg; j < end; ++j) {
        float v = (float)__builtin_nontemporal_load(outj2h + (size_t)j * 64 + lane);
        float a = alpha2s[(size_t)j * 2 + b];
        acc = fmaf(v, __expf(a - mb) * rs, acc);
    }
    h2[(size_t)w * 64 + lane] = acc;
}

__global__ void k_out(const float* h2, const float* lin2_w, const float* lin2_b,
                      float* out) {
    int n = blockIdx.x * blockDim.x + threadIdx.x;
    if (n >= NN) return;
    float o[4] = {lin2_b[0], lin2_b[1], lin2_b[2], lin2_b[3]};
    const float* hr = h2 + (size_t)n * 64;
    for (int c = 0; c < 64; ++c) {
        float hv = hr[c];
#pragma unroll
        for (int t = 0; t < 4; ++t) o[t] = fmaf(hv, lin2_w[c * 4 + t], o[t]);
    }
    float m = fmaxf(fmaxf(o[0], o[1]), fmaxf(o[2], o[3]));
    float s = __expf(o[0] - m) + __expf(o[1] - m) + __expf(o[2] - m) + __expf(o[3] - m);
    float lse = m + logf(s);
#pragma unroll
    for (int t = 0; t < 4; ++t) out[(size_t)n * 4 + t] = o[t] - lse;
}

extern "C" void kernel_launch(void* const* d_in, const int* in_sizes, int n_in,
                              void* d_out, int out_size, void* d_ws, size_t ws_size,
                              hipStream_t stream) {
    const float* x        = (const float*)d_in[0];
    const int*   eidx     = (const int*)d_in[1];
    const int*   etype    = (const int*)d_in[2];
    const float* eattr    = (const float*)d_in[3];
    const float* lin1_w   = (const float*)d_in[4];
    const float* att1     = (const float*)d_in[5];
    const float* basis1   = (const float*)d_in[6];
    const float* q1       = (const float*)d_in[7];
    const float* k1       = (const float*)d_in[8];
    const float* wmod1    = (const float*)d_in[9];
    const float* bias1    = (const float*)d_in[10];
    const float* w2       = (const float*)d_in[11];
    const float* q2       = (const float*)d_in[12];
    const float* k2       = (const float*)d_in[13];
    const float* lew      = (const float*)d_in[14];
    const float* e2i      = (const float*)d_in[15];
    const float* lin2_w   = (const float*)d_in[16];
    const float* lin2_b   = (const float*)d_in[17];

    const int* src = eidx;
    const int* dst = eidx + EE;

    // ---------------- workspace layout (f32 units) ----------------
    float* W = (float*)d_ws;
    float* w1      = W;   W += 230400;
    float* wq1     = W;   W += 23040;
    float* wk1     = W;   W += 23040;
    float* wq2     = W;   W += 14400;
    float* wk2     = W;   W += 14400;
    float* we      = W;   W += 32;
    float* h2      = W;   W += (size_t)NN * 64;
    float* aeS     = W;   W += (size_t)E2 * 2;
    f16*   hh      = (f16*)W;   W += (size_t)NN * 64 / 2;        // N*64 f16 (logits+MFMA)
    f16*   h1h     = (f16*)W;   W += (size_t)NN * 80 / 2 + 32;   // N*80 f16 + 64-elem pad
    f16*   w1hT    = (f16*)W;   W += (size_t)RR * 48 * 64 / 2;
    f16*   w2hT    = (f16*)W;   W += (size_t)RR * 2 * 32 * 64 / 2;
    // union region: conv1 {outj1h[EE*40 f16], alpha1s[EE*4 f32]} / conv2 {outj2h[EE*64 f16]}
    float* uni     = W;   W += (size_t)EE * 20 + (size_t)EE * 4;  // 24 f32-units/edge
    f16*   outj1h  = (f16*)uni;
    float* alpha1s = uni + (size_t)EE * 20;
    f16*   outj2h  = (f16*)uni;
    W += (size_t)EE * 8;                   // extend union to EE*32 f32 for outj2h
    float* alpha2s = W;   W += (size_t)EE * 2;
    int4*  sortedR = (int4*)W;
    int*   I = (int*)W;   I += (size_t)E2 * 4;
    u16*   relD    = (u16*)I;   I += (size_t)E2 / 2;
    int*   posS    = I;   I += EE;
    int*   rowptrD = I;   I += NN + 1;
    int*   cursorD = I;   I += NN;
    int*   histD   = I;   I += NN;    // zeroed block starts here
    int*   hist    = I;   I += 128;
    int*   cursor  = I;   I += 128;

    // ---------------- init ----------------
    hipMemsetAsync(histD, 0, (size_t)(NN + 256) * 4, stream);
    hipMemsetAsync(h1h + (size_t)NN * 80, 0, 128, stream);  // zero K-pad tail
    k_fillrec<<<E2 / 256, 256, 0, stream>>>(sortedR, E2);

    // sorts
    k_hist<<<EE / 256, 256, 0, stream>>>(etype, hist);
    k_scanPad<<<1, 64, 0, stream>>>(hist, cursor);
    k_scatter<<<EE / 256, 256, 0, stream>>>(src, dst, etype, cursor, sortedR, posS);
    k_histD<<<EE / 256, 256, 0, stream>>>(dst, histD);
    k_scanD<<<1, 256, 0, stream>>>(histD, rowptrD, cursorD);
    k_scatterD<<<E2 / 256, 256, 0, stream>>>(sortedR, cursorD, relD);

    // folded weights + f16 prep + dense input layer + edge-attr logits
    k_w1<<<(RR * 2560 + 255) / 256, 256, 0, stream>>>(att1, basis1, w1);
    k_wqk1<<<(RR * 256 + 255) / 256, 256, 0, stream>>>(w1, q1, k1, wq1, wk1);
    k_wqk2<<<(RR * 160 + 255) / 256, 256, 0, stream>>>(w2, q2, k2, wq2, wk2);
    k_we<<<1, 32, 0, stream>>>(lew, e2i, we);
    k_ae<<<EE / 256, 256, 0, stream>>>(eattr, we, posS, aeS);
    k_w1hT<<<(RR * 48 * 64) / 256, 256, 0, stream>>>(w1, w1hT);
    k_w2hT<<<(RR * 2 * 32 * 64) / 256, 256, 0, stream>>>(w2, w2hT);
    k_h<<<NN, 64, 0, stream>>>(x, lin1_w, hh);

    // conv1 (fused logits + transform; 64 edges/wave, depth-2 pipeline)
    k_c1<<<E2 / 256, 256, 0, stream>>>(sortedR, hh, w1hT, wq1, wk1, alpha1s, outj1h);
    k_aggr1<<<NN / 4, 256, 0, stream>>>(relD, rowptrD, outj1h, alpha1s,
                                        wmod1, bias1, h1h);

    // conv2 (fused; outj2h aliases dead conv1 buffers)
    k_c2<<<E2 / 256, 256, 0, stream>>>(sortedR, h1h, w2hT, wq2, wk2, aeS,
                                       alpha2s, outj2h);
    k_aggr2<<<(NN + 3) / 4, 256, 0, stream>>>(rowptrD, outj2h, alpha2s, h2);

    k_out<<<(NN + 255) / 256, 256, 0, stream>>>(h2, lin2_w, lin2_b, (float*)d_out);
}